// Round 7
// baseline (786.478 us; speedup 1.0000x reference)
//
#include <hip/hip_runtime.h>
#include <hip/hip_bf16.h>

// ConceptBottleneck fused kernel, MI355X (gfx950).
// B=8192, IN=768, C=64, H=64, E=16.  Inputs/outputs fp32; internal math bf16 MFMA.
// prep_all: ONE flat-grid launch — LDS-tiled transposes of [K x 64] weights plus
//           grid-strided fp32->bf16 copies / small strided transposes.
// cb_fused_t: grid (B/128, C); block = 128-row batch tile x one concept.
//   SPLIT-BANK L1 (R3 structure: 38.4 KB LDS -> 4 blocks/CU; accP/accN never
//   co-live -> low VGPR pressure) + register prefetch of the next K-tile.
//   SPILL SAGA: default heuristic / __launch_bounds__(256,{2,3}) let LLVM chase
//   6 waves/EU by spilling acc regs -> 1.3-1.6 GB phantom HBM writebacks
//   (R4/R5). amdgpu_waves_per_eu max is the binding knob (R6: fixed).
//   Here (2,4): budget 256 (no forced spill), HW occupancy from actual VGPRs.

#define B_   8192
#define IN_  768
#define C_   64
#define H_   64
#define E_   16
#define BM_  128

typedef __bf16 bf16x8 __attribute__((ext_vector_type(8)));
typedef float  f32x4  __attribute__((ext_vector_type(4)));

__device__ __forceinline__ f32x4 mfma16(bf16x8 a, bf16x8 b, f32x4 c) {
  return __builtin_amdgcn_mfma_f32_16x16x32_bf16(a, b, c, 0, 0, 0);
}

__device__ __forceinline__ bf16x8 cvt8(float4 a, float4 b) {
  bf16x8 r;
  r[0] = (__bf16)a.x; r[1] = (__bf16)a.y; r[2] = (__bf16)a.z; r[3] = (__bf16)a.w;
  r[4] = (__bf16)b.x; r[5] = (__bf16)b.y; r[6] = (__bf16)b.z; r[7] = (__bf16)b.w;
  return r;
}

__device__ __forceinline__ void zero_acc(f32x4 (&acc)[2][4]) {
  const f32x4 z = {0.f, 0.f, 0.f, 0.f};
#pragma unroll
  for (int mt = 0; mt < 2; ++mt)
#pragma unroll
    for (int nt = 0; nt < 4; ++nt) acc[mt][nt] = z;
}

// ============================ MAIN KERNEL ===================================
// LDS (38400 B -> 4 blocks/CU):
//  xs [128][72] : x tile during L1; aliased as hb (activations) afterwards
//  wt [64][72]  : weight tile in [n][k] layout (phase-multiplexed)
//  xcb[128][40] : pos|neg embeddings (cols 0..15 pos, 16..31 neg)
struct __align__(16) SmemT {
  __bf16 xs[BM_ * 72];
  __bf16 wt[64 * 72];
  __bf16 xcb[BM_ * 40];
  float  conc[BM_];
};
static_assert(sizeof(SmemT) <= 40960, "LDS overflow");

// Epilogue: C/D frags (col=lane&15, row=quad*4+reg) + fp32 bias, relu -> hb (stride 72)
__device__ __forceinline__ void epi72(__bf16* __restrict__ hb, f32x4 (&acc)[2][4],
                                      const float* __restrict__ bias,
                                      int wave, int quad, int l16) {
#pragma unroll
  for (int nt = 0; nt < 4; ++nt) {
    const int col = nt * 16 + l16;
    const float bv = bias[col];
#pragma unroll
    for (int mt = 0; mt < 2; ++mt)
#pragma unroll
      for (int r = 0; r < 4; ++r) {
        int row = wave * 32 + mt * 16 + quad * 4 + r;
        hb[row * 72 + col] = (__bf16)fmaxf(acc[mt][nt][r] + bv, 0.f);
      }
  }
}

// [128,64] @ [64,64]: A=hb (stride 72), B=wt [n][k] (stride 72), K=64.
__device__ __forceinline__ void gemm64(const __bf16* __restrict__ hb,
                                       const __bf16* __restrict__ wt,
                                       f32x4 (&acc)[2][4], int wave, int quad, int l16) {
#pragma unroll
  for (int ks = 0; ks < 2; ++ks) {
    bf16x8 a[2], bb[4];
#pragma unroll
    for (int mt = 0; mt < 2; ++mt)
      a[mt] = *(const bf16x8*)(hb + (wave * 32 + mt * 16 + l16) * 72 + ks * 32 + quad * 8);
#pragma unroll
    for (int nt = 0; nt < 4; ++nt)
      bb[nt] = *(const bf16x8*)(wt + (nt * 16 + l16) * 72 + ks * 32 + quad * 8);
#pragma unroll
    for (int mt = 0; mt < 2; ++mt)
#pragma unroll
      for (int nt = 0; nt < 4; ++nt)
        acc[mt][nt] = mfma16(a[mt], bb[nt], acc[mt][nt]);
  }
}

// Stage [64][64] bf16 tile (row-major contiguous) into wt (stride 72). 2 b128/thread.
__device__ __forceinline__ void stage_w64(const __bf16* __restrict__ Wt,
                                          __bf16* __restrict__ wt, int tid) {
#pragma unroll
  for (int it = 0; it < 2; ++it) {
    int q = tid + it * 256;
    int n = q >> 3, i = q & 7;
    *(uint4*)&wt[n * 72 + i * 8] = *(const uint4*)(Wt + n * 64 + i * 8);
  }
}

// One bank: h1=relu(x@W1+b1); h2=relu(h1@W2+b2); e=h2@W3+b3 -> xcb[:, xc_off..+16)
// W1t: [64][768], W2t: [64][64], W3t: [16][64]  (transposed, bf16)
__device__ __forceinline__ void run_bank_t(SmemT& sm, const __bf16* __restrict__ x,
    const __bf16* __restrict__ W1t, const float* __restrict__ b1,
    const __bf16* __restrict__ W2t, const float* __restrict__ b2,
    const __bf16* __restrict__ W3t, const float* __restrict__ b3,
    int row0, int xc_off, int tid, int wave, int quad, int l16)
{
  __bf16* xs = sm.xs;
  __bf16* wt = sm.wt;
  __bf16* hb = sm.xs;   // alias: xs dead after L1 loop's final barrier

  // ---------- layer 1: [128,768] @ [768,64], BK=64, register prefetch ----------
  f32x4 acc1[2][4]; zero_acc(acc1);
  const int sr = tid >> 3, si = tid & 7;   // stage coords: 32 rows x 8 chunks of 16B
  const __bf16* xg = x + (size_t)row0 * IN_;
  uint4 xv[4], wv[2];
#pragma unroll
  for (int it = 0; it < 4; ++it)
    xv[it] = *(const uint4*)(xg + (size_t)(sr + it * 32) * IN_ + si * 8);
#pragma unroll
  for (int it = 0; it < 2; ++it)
    wv[it] = *(const uint4*)(W1t + (size_t)(sr + it * 32) * IN_ + si * 8);

  for (int kt = 0; kt < IN_ / 64; ++kt) {
#pragma unroll
    for (int it = 0; it < 4; ++it)
      *(uint4*)&xs[(sr + it * 32) * 72 + si * 8] = xv[it];
#pragma unroll
    for (int it = 0; it < 2; ++it)
      *(uint4*)&wt[(sr + it * 32) * 72 + si * 8] = wv[it];
    __syncthreads();
    if (kt + 1 < IN_ / 64) {               // prefetch next tile under the MFMAs
      const int ko = (kt + 1) * 64;
#pragma unroll
      for (int it = 0; it < 4; ++it)
        xv[it] = *(const uint4*)(xg + (size_t)(sr + it * 32) * IN_ + ko + si * 8);
#pragma unroll
      for (int it = 0; it < 2; ++it)
        wv[it] = *(const uint4*)(W1t + (size_t)(sr + it * 32) * IN_ + ko + si * 8);
    }
#pragma unroll
    for (int ks = 0; ks < 2; ++ks) {
      bf16x8 a[2], bb[4];
#pragma unroll
      for (int mt = 0; mt < 2; ++mt)
        a[mt] = *(const bf16x8*)&xs[(wave * 32 + mt * 16 + l16) * 72 + ks * 32 + quad * 8];
#pragma unroll
      for (int nt = 0; nt < 4; ++nt)
        bb[nt] = *(const bf16x8*)&wt[(nt * 16 + l16) * 72 + ks * 32 + quad * 8];
#pragma unroll
      for (int mt = 0; mt < 2; ++mt)
#pragma unroll
        for (int nt = 0; nt < 4; ++nt)
          acc1[mt][nt] = mfma16(a[mt], bb[nt], acc1[mt][nt]);
    }
    __syncthreads();
  }
  epi72(hb, acc1, b1, wave, quad, l16);   // writes xs region (reads drained)
  stage_w64(W2t, wt, tid);                // disjoint region, same phase
  __syncthreads();

  // ---------- layer 2: [128,64] @ [64,64] ----------
  f32x4 acc2[2][4]; zero_acc(acc2);
  gemm64(hb, wt, acc2, wave, quad, l16);
  __syncthreads();
  epi72(hb, acc2, b2, wave, quad, l16);
  if (tid < 128)                          // stage W3t [16][64]
    *(uint4*)&wt[(tid >> 3) * 72 + (tid & 7) * 8] =
        *(const uint4*)(W3t + (tid >> 3) * 64 + (tid & 7) * 8);
  __syncthreads();

  // ---------- layer 3: [128,64] @ [64,16] ----------
  f32x4 acc3[2];
  { const f32x4 z = {0.f, 0.f, 0.f, 0.f}; acc3[0] = z; acc3[1] = z; }
#pragma unroll
  for (int ks = 0; ks < 2; ++ks) {
    bf16x8 bb = *(const bf16x8*)&wt[l16 * 72 + ks * 32 + quad * 8];
#pragma unroll
    for (int mt = 0; mt < 2; ++mt) {
      bf16x8 a = *(const bf16x8*)&hb[(wave * 32 + mt * 16 + l16) * 72 + ks * 32 + quad * 8];
      acc3[mt] = mfma16(a, bb, acc3[mt]);
    }
  }
  {
    float bv = b3[l16];
#pragma unroll
    for (int mt = 0; mt < 2; ++mt)
#pragma unroll
      for (int r = 0; r < 4; ++r) {
        int row = wave * 32 + mt * 16 + quad * 4 + r;
        sm.xcb[row * 40 + xc_off + l16] = (__bf16)(acc3[mt][r] + bv);
      }
  }
  __syncthreads();
}

__global__ __launch_bounds__(256)
__attribute__((amdgpu_waves_per_eu(2, 4)))
void cb_fused_t(
    const __bf16* __restrict__ x,
    const __bf16* __restrict__ pW1t, const float* __restrict__ pb1,
    const __bf16* __restrict__ pW2t, const float* __restrict__ pb2,
    const __bf16* __restrict__ pW3t, const float* __restrict__ pb3,
    const __bf16* __restrict__ nW1t, const float* __restrict__ nb1,
    const __bf16* __restrict__ nW2t, const float* __restrict__ nb2,
    const __bf16* __restrict__ nW3t, const float* __restrict__ nb3,
    const __bf16* __restrict__ cW1t, const float* __restrict__ cb1,
    const __bf16* __restrict__ cW2t, const float* __restrict__ cb2,
    const __bf16* __restrict__ cw3,  const float* __restrict__ cb3,
    float* __restrict__ out_emb, float* __restrict__ out_con)
{
  __shared__ SmemT sm;
  const int tid  = threadIdx.x;
  const int wave = tid >> 6, lane = tid & 63;
  const int quad = lane >> 4, l16 = lane & 15;
  const int row0 = blockIdx.x * BM_;
  const int c    = blockIdx.y;
  __bf16* hb = sm.xs;
  __bf16* wt = sm.wt;

  run_bank_t(sm, x, pW1t + (size_t)c * 64 * IN_, pb1 + c * 64,
             pW2t + (size_t)c * 64 * 64, pb2 + c * 64,
             pW3t + (size_t)c * 16 * 64, pb3 + c * 16,
             row0, 0, tid, wave, quad, l16);
  run_bank_t(sm, x, nW1t + (size_t)c * 64 * IN_, nb1 + c * 64,
             nW2t + (size_t)c * 64 * 64, nb2 + c * 64,
             nW3t + (size_t)c * 16 * 64, nb3 + c * 16,
             row0, 16, tid, wave, quad, l16);

  // ---- cp layer 1: [128,32] @ [32,64]; A = xcb (stride 40), B = cW1t [64][32] ----
  {
    int n = tid >> 2, i = tid & 3;
    *(uint4*)&wt[n * 72 + i * 8] = *(const uint4*)(cW1t + ((size_t)c * 64 + n) * 32 + i * 8);
  }
  __syncthreads();
  f32x4 acc1[2][4]; zero_acc(acc1);
  {
    bf16x8 a[2], bb[4];
#pragma unroll
    for (int mt = 0; mt < 2; ++mt)
      a[mt] = *(const bf16x8*)&sm.xcb[(wave * 32 + mt * 16 + l16) * 40 + quad * 8];
#pragma unroll
    for (int nt = 0; nt < 4; ++nt)
      bb[nt] = *(const bf16x8*)&wt[(nt * 16 + l16) * 72 + quad * 8];
#pragma unroll
    for (int mt = 0; mt < 2; ++mt)
#pragma unroll
      for (int nt = 0; nt < 4; ++nt)
        acc1[mt][nt] = mfma16(a[mt], bb[nt], acc1[mt][nt]);
  }
  __syncthreads();
  epi72(hb, acc1, cb1 + c * 64, wave, quad, l16);
  stage_w64(cW2t + (size_t)c * 64 * 64, wt, tid);
  __syncthreads();

  // ---- cp layer 2 ----
  f32x4 acc2[2][4]; zero_acc(acc2);
  gemm64(hb, wt, acc2, wave, quad, l16);
  __syncthreads();
  epi72(hb, acc2, cb2 + c * 64, wave, quad, l16);
  if (tid < 8) *(uint4*)&wt[tid * 8] = *(const uint4*)(cw3 + (size_t)c * 64 + tid * 8);
  __syncthreads();

  // ---- cp layer 3 (N=1 via MFMA; B nonzero only in lane col 0) ----
  f32x4 acc3[2];
  { const f32x4 z = {0.f, 0.f, 0.f, 0.f}; acc3[0] = z; acc3[1] = z; }
#pragma unroll
  for (int ks = 0; ks < 2; ++ks) {
    bf16x8 bb = {};
    if (l16 == 0) bb = *(const bf16x8*)&wt[ks * 32 + quad * 8];
#pragma unroll
    for (int mt = 0; mt < 2; ++mt) {
      bf16x8 a = *(const bf16x8*)&hb[(wave * 32 + mt * 16 + l16) * 72 + ks * 32 + quad * 8];
      acc3[mt] = mfma16(a, bb, acc3[mt]);
    }
  }
  if (l16 == 0) {
    float bv = cb3[c];
#pragma unroll
    for (int mt = 0; mt < 2; ++mt)
#pragma unroll
      for (int r = 0; r < 4; ++r)
        sm.conc[wave * 32 + mt * 16 + quad * 4 + r] = acc3[mt][r] + bv;
  }
  __syncthreads();

  // ---- gate + outputs (fp32) ----
  for (int ii = tid; ii < BM_ * E_; ii += 256) {
    int row = ii >> 4, e = ii & 15;
    float cv = sm.conc[row];
    float w  = fminf(fmaxf(cv * 0.5f + 0.5f, 0.f), 1.f);
    float pv2 = (float)sm.xcb[row * 40 + e];
    float nv2 = (float)sm.xcb[row * 40 + 16 + e];
    out_emb[(size_t)(row0 + row) * (E_ * C_) + e * C_ + c] = pv2 * w + nv2 * (1.f - w);
  }
  if (tid < 128) out_con[(size_t)(row0 + tid) * C_ + c] = sm.conc[tid];
}

// ------------- prep_all: ONE flat 1D launch, no dead blocks -------------------
// Blocks [0, tblocks): LDS-tiled transpose of [C][K][64] fp32 -> [C][64][K] bf16.
// Blocks [tblocks, ..): grid-strided (4 chunks/thread) fp32->bf16 copies and
//   small strided transposes.
#define TSEG 5
#define PSEG 5
struct PrepArgs {
  const float* tsrc[TSEG];
  __bf16*      tdst[TSEG];
  int tstart[TSEG + 1];
  int ktiles[TSEG];            // K/64
  const float* psrc[PSEG];
  __bf16*      pdst[PSEG];
  int pstart[PSEG + 1];        // block starts (after tblocks)
  int pchunks[PSEG];           // total 8-elem chunks in segment
  int kdiv8[PSEG];
  int N[PSEG];                 // 1 = plain copy, else transpose inner stride
  int tblocks;
};

__global__ __launch_bounds__(256) void prep_all(PrepArgs a) {
  const int tid = threadIdx.x;
  const int b = blockIdx.x;
  __shared__ __bf16 lt[64 * 72];
  if (b < a.tblocks) {
    int s = 0;
    while (s < TSEG - 1 && b >= a.tstart[s + 1]) ++s;
    const int idx = b - a.tstart[s];
    const int kt = idx % a.ktiles[s];
    const int c  = idx / a.ktiles[s];
    const int K  = a.ktiles[s] * 64;
    const float* src = a.tsrc[s] + (size_t)c * K * 64 + (size_t)kt * 64 * 64;
    __bf16*      dst = a.tdst[s] + (size_t)c * 64 * K + kt * 64;
    const int r = tid >> 4, c4 = (tid & 15) * 4;
#pragma unroll
    for (int it = 0; it < 4; ++it) {
      int k = r + it * 16;
      float4 v = *(const float4*)(src + (size_t)k * 64 + c4);
      lt[(c4 + 0) * 72 + k] = (__bf16)v.x;
      lt[(c4 + 1) * 72 + k] = (__bf16)v.y;
      lt[(c4 + 2) * 72 + k] = (__bf16)v.z;
      lt[(c4 + 3) * 72 + k] = (__bf16)v.w;
    }
    __syncthreads();
    const int n = tid >> 3, i = tid & 7;
#pragma unroll
    for (int it = 0; it < 2; ++it) {
      int nn = n + it * 32;
      *(uint4*)(dst + (size_t)nn * K + i * 8) = *(const uint4*)&lt[nn * 72 + i * 8];
    }
  } else {
    const int bb = b - a.tblocks;
    int s = 0;
    while (s < PSEG - 1 && bb >= a.pstart[s + 1]) ++s;
    const int lb  = bb - a.pstart[s];
    const int nch = a.pchunks[s];
    const int kc  = a.kdiv8[s];
    const int N   = a.N[s];
#pragma unroll
    for (int j = 0; j < 4; ++j) {
      const int li = (lb * 4 + j) * 256 + tid;
      if (li >= nch) break;
      if (N == 1) {
        const float4* src = (const float4*)a.psrc[s] + (size_t)li * 2;
        float4 v0 = src[0], v1 = src[1];
        *(uint4*)(a.pdst[s] + (size_t)li * 8) = __builtin_bit_cast(uint4, cvt8(v0, v1));
      } else {
        int rn = li / kc;
        int k0 = (li - rn * kc) * 8;
        int cc = rn / N;
        int n  = rn - cc * N;
        const float* src = a.psrc[s] + ((size_t)cc * kc * 8 + k0) * N + n;
        bf16x8 r;
#pragma unroll
        for (int jj = 0; jj < 8; ++jj) r[jj] = (__bf16)src[(size_t)jj * N];
        *(uint4*)(a.pdst[s] + (size_t)rn * kc * 8 + k0) = __builtin_bit_cast(uint4, r);
      }
    }
  }
}

// ============================== launch =======================================
extern "C" void kernel_launch(void* const* d_in, const int* in_sizes, int n_in,
                              void* d_out, int out_size, void* d_ws, size_t ws_size,
                              hipStream_t stream) {
  const float* xf   = (const float*)d_in[0];
  const float* pW1f = (const float*)d_in[1];
  const float* pb1f = (const float*)d_in[2];
  const float* pW2f = (const float*)d_in[3];
  const float* pb2f = (const float*)d_in[4];
  const float* pW3f = (const float*)d_in[5];
  const float* pb3f = (const float*)d_in[6];
  const float* nW1f = (const float*)d_in[7];
  const float* nb1f = (const float*)d_in[8];
  const float* nW2f = (const float*)d_in[9];
  const float* nb2f = (const float*)d_in[10];
  const float* nW3f = (const float*)d_in[11];
  const float* nb3f = (const float*)d_in[12];
  const float* cW1f = (const float*)d_in[13];
  const float* cb1f = (const float*)d_in[14];
  const float* cW2f = (const float*)d_in[15];
  const float* cb2f = (const float*)d_in[16];
  const float* cW3f = (const float*)d_in[17];
  const float* cb3f = (const float*)d_in[18];

  float* out_emb = (float*)d_out;
  float* out_con = out_emb + (size_t)B_ * E_ * C_;

  const int cx   = B_ * IN_;          // 6291456
  const int cW1c = C_ * IN_ * H_;     // 3145728
  const int cW2c = C_ * H_ * H_;      // 262144
  const int cW3c = C_ * H_ * E_;      // 65536
  const int ccW1 = C_ * 2 * E_ * H_;  // 131072
  const int ccW3 = C_ * H_;           // 4096

  __bf16* w = (__bf16*)d_ws;
  size_t o = 0;
  __bf16* xw   = w + o; o += cx;
  __bf16* pw1t = w + o; o += cW1c;
  __bf16* nw1t = w + o; o += cW1c;
  __bf16* pw2t = w + o; o += cW2c;
  __bf16* nw2t = w + o; o += cW2c;
  __bf16* cw2t = w + o; o += cW2c;
  __bf16* pw3t = w + o; o += cW3c;
  __bf16* nw3t = w + o; o += cW3c;
  __bf16* cw1t = w + o; o += ccW1;
  __bf16* cw3w = w + o; o += ccW3;

  PrepArgs a;
  int tb = 0, pb = 0;
  {
    const float* tsrc[TSEG] = {pW1f, nW1f, pW2f, nW2f, cW2f};
    __bf16*      tdst[TSEG] = {pw1t, nw1t, pw2t, nw2t, cw2t};
    const int    tk[TSEG]   = {12,   12,   1,    1,    1};
    for (int i = 0; i < TSEG; ++i) {
      a.tsrc[i] = tsrc[i]; a.tdst[i] = tdst[i]; a.ktiles[i] = tk[i];
      a.tstart[i] = tb;
      tb += tk[i] * C_;
    }
    a.tstart[TSEG] = tb;
    a.tblocks = tb;

    const float* psrc[PSEG] = {xf, cW3f, pW3f, nW3f, cW1f};
    __bf16*      pdst[PSEG] = {xw, cw3w, pw3t, nw3t, cw1t};
    const int    pKs[PSEG]  = {0,  0,    64,   64,   32};
    const int    pNs[PSEG]  = {1,  1,    16,   16,   64};
    const int    pels[PSEG] = {cx, ccW3, cW3c, cW3c, ccW1};
    for (int i = 0; i < PSEG; ++i) {
      a.psrc[i] = psrc[i]; a.pdst[i] = pdst[i];
      a.pchunks[i] = pels[i] / 8;
      a.kdiv8[i] = (pNs[i] == 1) ? (pels[i] / 8) : (pKs[i] / 8);
      a.N[i] = pNs[i];
      a.pstart[i] = pb;
      pb += (pels[i] / 8 + 1023) / 1024;   // 256 threads x 4 chunks per block
    }
    a.pstart[PSEG] = pb;
  }
  prep_all<<<tb + pb, 256, 0, stream>>>(a);

  dim3 grid(B_ / BM_, C_);
  cb_fused_t<<<grid, 256, 0, stream>>>(xw,
      pw1t, pb1f, pw2t, pb2f, pw3t, pb3f,
      nw1t, nb1f, nw2t, nb2f, nw3t, nb3f,
      cw1t, cb1f, cw2t, cb2f, cw3w, cb3f,
      out_emb, out_con);
}

// Round 8
// 335.275 us; speedup vs baseline: 2.3458x; 2.3458x over previous
//
#include <hip/hip_runtime.h>
#include <hip/hip_bf16.h>

// ConceptBottleneck fused kernel, MI355X (gfx950).
// B=8192, IN=768, C=64, H=64, E=16.  Inputs/outputs fp32; internal math bf16 MFMA.
// prep_all: ONE flat-grid launch — LDS-tiled transposes of [K x 64] weights plus
//           grid-strided fp32->bf16 copies / small strided transposes.
// cb_fused_t: grid (B/128, C); block = 128-row batch tile x one concept.
//   EXACT R3 structure (best verified: 234 us, VGPR 60, no spills, 4 blocks/CU).
//   SPILL LAW (R4/R5/R7): any register state held live across __syncthreads
//   beyond the accumulators gets spilled to scratch by this compiler, under
//   launch_bounds(256,{2,3}) AND amdgpu_waves_per_eu(2,{3,4}) alike ->
//   1.3-2.1 GB phantom HBM writebacks. NO cross-barrier prefetch. Loads are
//   issued at the top of each K-iteration and consumed immediately.

#define B_   8192
#define IN_  768
#define C_   64
#define H_   64
#define E_   16
#define BM_  128

typedef __bf16 bf16x8 __attribute__((ext_vector_type(8)));
typedef float  f32x4  __attribute__((ext_vector_type(4)));

__device__ __forceinline__ f32x4 mfma16(bf16x8 a, bf16x8 b, f32x4 c) {
  return __builtin_amdgcn_mfma_f32_16x16x32_bf16(a, b, c, 0, 0, 0);
}

__device__ __forceinline__ bf16x8 cvt8(float4 a, float4 b) {
  bf16x8 r;
  r[0] = (__bf16)a.x; r[1] = (__bf16)a.y; r[2] = (__bf16)a.z; r[3] = (__bf16)a.w;
  r[4] = (__bf16)b.x; r[5] = (__bf16)b.y; r[6] = (__bf16)b.z; r[7] = (__bf16)b.w;
  return r;
}

__device__ __forceinline__ void zero_acc(f32x4 (&acc)[2][4]) {
  const f32x4 z = {0.f, 0.f, 0.f, 0.f};
#pragma unroll
  for (int mt = 0; mt < 2; ++mt)
#pragma unroll
    for (int nt = 0; nt < 4; ++nt) acc[mt][nt] = z;
}

// ============================ MAIN KERNEL ===================================
// LDS (38400 B -> 4 blocks/CU):
//  xs [128][72] : x tile during L1; aliased as hb (activations) afterwards
//  wt [64][72]  : weight tile in [n][k] layout (phase-multiplexed)
//  xcb[128][40] : pos|neg embeddings (cols 0..15 pos, 16..31 neg)
struct __align__(16) SmemT {
  __bf16 xs[BM_ * 72];
  __bf16 wt[64 * 72];
  __bf16 xcb[BM_ * 40];
  float  conc[BM_];
};
static_assert(sizeof(SmemT) <= 40960, "LDS overflow");

// Epilogue: C/D frags (col=lane&15, row=quad*4+reg) + fp32 bias, relu -> hb (stride 72)
__device__ __forceinline__ void epi72(__bf16* __restrict__ hb, f32x4 (&acc)[2][4],
                                      const float* __restrict__ bias,
                                      int wave, int quad, int l16) {
#pragma unroll
  for (int nt = 0; nt < 4; ++nt) {
    const int col = nt * 16 + l16;
    const float bv = bias[col];
#pragma unroll
    for (int mt = 0; mt < 2; ++mt)
#pragma unroll
      for (int r = 0; r < 4; ++r) {
        int row = wave * 32 + mt * 16 + quad * 4 + r;
        hb[row * 72 + col] = (__bf16)fmaxf(acc[mt][nt][r] + bv, 0.f);
      }
  }
}

// [128,64] @ [64,64]: A=hb (stride 72), B=wt [n][k] (stride 72), K=64.
__device__ __forceinline__ void gemm64(const __bf16* __restrict__ hb,
                                       const __bf16* __restrict__ wt,
                                       f32x4 (&acc)[2][4], int wave, int quad, int l16) {
#pragma unroll
  for (int ks = 0; ks < 2; ++ks) {
    bf16x8 a[2], bb[4];
#pragma unroll
    for (int mt = 0; mt < 2; ++mt)
      a[mt] = *(const bf16x8*)(hb + (wave * 32 + mt * 16 + l16) * 72 + ks * 32 + quad * 8);
#pragma unroll
    for (int nt = 0; nt < 4; ++nt)
      bb[nt] = *(const bf16x8*)(wt + (nt * 16 + l16) * 72 + ks * 32 + quad * 8);
#pragma unroll
    for (int mt = 0; mt < 2; ++mt)
#pragma unroll
      for (int nt = 0; nt < 4; ++nt)
        acc[mt][nt] = mfma16(a[mt], bb[nt], acc[mt][nt]);
  }
}

// Stage [64][64] bf16 tile (row-major contiguous) into wt (stride 72). 2 b128/thread.
__device__ __forceinline__ void stage_w64(const __bf16* __restrict__ Wt,
                                          __bf16* __restrict__ wt, int tid) {
#pragma unroll
  for (int it = 0; it < 2; ++it) {
    int q = tid + it * 256;
    int n = q >> 3, i = q & 7;
    *(uint4*)&wt[n * 72 + i * 8] = *(const uint4*)(Wt + n * 64 + i * 8);
  }
}

// One bank: h1=relu(x@W1+b1); h2=relu(h1@W2+b2); e=h2@W3+b3 -> xcb[:, xc_off..+16)
// W1t: [64][768], W2t: [64][64], W3t: [16][64]  (transposed, bf16)
__device__ __forceinline__ void run_bank_t(SmemT& sm, const __bf16* __restrict__ x,
    const __bf16* __restrict__ W1t, const float* __restrict__ b1,
    const __bf16* __restrict__ W2t, const float* __restrict__ b2,
    const __bf16* __restrict__ W3t, const float* __restrict__ b3,
    int row0, int xc_off, int tid, int wave, int quad, int l16)
{
  __bf16* xs = sm.xs;
  __bf16* wt = sm.wt;
  __bf16* hb = sm.xs;   // alias: xs dead after L1 loop's final barrier

  // ---------- layer 1: [128,768] @ [768,64], BK=64 ----------
  f32x4 acc1[2][4]; zero_acc(acc1);
  const int sr = tid >> 3, si = tid & 7;   // stage coords: 32 rows x 8 chunks of 16B
  const __bf16* xg = x + (size_t)row0 * IN_;
  for (int kt = 0; kt < IN_ / 64; ++kt) {
    const int ko = kt * 64;
    uint4 xv[4], wv[2];
#pragma unroll
    for (int it = 0; it < 4; ++it)
      xv[it] = *(const uint4*)(xg + (size_t)(sr + it * 32) * IN_ + ko + si * 8);
#pragma unroll
    for (int it = 0; it < 2; ++it)
      wv[it] = *(const uint4*)(W1t + (size_t)(sr + it * 32) * IN_ + ko + si * 8);
#pragma unroll
    for (int it = 0; it < 4; ++it)
      *(uint4*)&xs[(sr + it * 32) * 72 + si * 8] = xv[it];
#pragma unroll
    for (int it = 0; it < 2; ++it)
      *(uint4*)&wt[(sr + it * 32) * 72 + si * 8] = wv[it];
    __syncthreads();
#pragma unroll
    for (int ks = 0; ks < 2; ++ks) {
      bf16x8 a[2], bb[4];
#pragma unroll
      for (int mt = 0; mt < 2; ++mt)
        a[mt] = *(const bf16x8*)&xs[(wave * 32 + mt * 16 + l16) * 72 + ks * 32 + quad * 8];
#pragma unroll
      for (int nt = 0; nt < 4; ++nt)
        bb[nt] = *(const bf16x8*)&wt[(nt * 16 + l16) * 72 + ks * 32 + quad * 8];
#pragma unroll
      for (int mt = 0; mt < 2; ++mt)
#pragma unroll
        for (int nt = 0; nt < 4; ++nt)
          acc1[mt][nt] = mfma16(a[mt], bb[nt], acc1[mt][nt]);
    }
    __syncthreads();
  }
  epi72(hb, acc1, b1, wave, quad, l16);   // writes xs region (reads drained)
  stage_w64(W2t, wt, tid);                // disjoint region, same phase
  __syncthreads();

  // ---------- layer 2: [128,64] @ [64,64] ----------
  f32x4 acc2[2][4]; zero_acc(acc2);
  gemm64(hb, wt, acc2, wave, quad, l16);
  __syncthreads();
  epi72(hb, acc2, b2, wave, quad, l16);
  if (tid < 128)                          // stage W3t [16][64]
    *(uint4*)&wt[(tid >> 3) * 72 + (tid & 7) * 8] =
        *(const uint4*)(W3t + (tid >> 3) * 64 + (tid & 7) * 8);
  __syncthreads();

  // ---------- layer 3: [128,64] @ [64,16] ----------
  f32x4 acc3[2];
  { const f32x4 z = {0.f, 0.f, 0.f, 0.f}; acc3[0] = z; acc3[1] = z; }
#pragma unroll
  for (int ks = 0; ks < 2; ++ks) {
    bf16x8 bb = *(const bf16x8*)&wt[l16 * 72 + ks * 32 + quad * 8];
#pragma unroll
    for (int mt = 0; mt < 2; ++mt) {
      bf16x8 a = *(const bf16x8*)&hb[(wave * 32 + mt * 16 + l16) * 72 + ks * 32 + quad * 8];
      acc3[mt] = mfma16(a, bb, acc3[mt]);
    }
  }
  {
    float bv = b3[l16];
#pragma unroll
    for (int mt = 0; mt < 2; ++mt)
#pragma unroll
      for (int r = 0; r < 4; ++r) {
        int row = wave * 32 + mt * 16 + quad * 4 + r;
        sm.xcb[row * 40 + xc_off + l16] = (__bf16)(acc3[mt][r] + bv);
      }
  }
  __syncthreads();
}

__global__ __launch_bounds__(256, 4) void cb_fused_t(
    const __bf16* __restrict__ x,
    const __bf16* __restrict__ pW1t, const float* __restrict__ pb1,
    const __bf16* __restrict__ pW2t, const float* __restrict__ pb2,
    const __bf16* __restrict__ pW3t, const float* __restrict__ pb3,
    const __bf16* __restrict__ nW1t, const float* __restrict__ nb1,
    const __bf16* __restrict__ nW2t, const float* __restrict__ nb2,
    const __bf16* __restrict__ nW3t, const float* __restrict__ nb3,
    const __bf16* __restrict__ cW1t, const float* __restrict__ cb1,
    const __bf16* __restrict__ cW2t, const float* __restrict__ cb2,
    const __bf16* __restrict__ cw3,  const float* __restrict__ cb3,
    float* __restrict__ out_emb, float* __restrict__ out_con)
{
  __shared__ SmemT sm;
  const int tid  = threadIdx.x;
  const int wave = tid >> 6, lane = tid & 63;
  const int quad = lane >> 4, l16 = lane & 15;
  const int row0 = blockIdx.x * BM_;
  const int c    = blockIdx.y;
  __bf16* hb = sm.xs;
  __bf16* wt = sm.wt;

  run_bank_t(sm, x, pW1t + (size_t)c * 64 * IN_, pb1 + c * 64,
             pW2t + (size_t)c * 64 * 64, pb2 + c * 64,
             pW3t + (size_t)c * 16 * 64, pb3 + c * 16,
             row0, 0, tid, wave, quad, l16);
  run_bank_t(sm, x, nW1t + (size_t)c * 64 * IN_, nb1 + c * 64,
             nW2t + (size_t)c * 64 * 64, nb2 + c * 64,
             nW3t + (size_t)c * 16 * 64, nb3 + c * 16,
             row0, 16, tid, wave, quad, l16);

  // ---- cp layer 1: [128,32] @ [32,64]; A = xcb (stride 40), B = cW1t [64][32] ----
  {
    int n = tid >> 2, i = tid & 3;
    *(uint4*)&wt[n * 72 + i * 8] = *(const uint4*)(cW1t + ((size_t)c * 64 + n) * 32 + i * 8);
  }
  __syncthreads();
  f32x4 acc1[2][4]; zero_acc(acc1);
  {
    bf16x8 a[2], bb[4];
#pragma unroll
    for (int mt = 0; mt < 2; ++mt)
      a[mt] = *(const bf16x8*)&sm.xcb[(wave * 32 + mt * 16 + l16) * 40 + quad * 8];
#pragma unroll
    for (int nt = 0; nt < 4; ++nt)
      bb[nt] = *(const bf16x8*)&wt[(nt * 16 + l16) * 72 + quad * 8];
#pragma unroll
    for (int mt = 0; mt < 2; ++mt)
#pragma unroll
      for (int nt = 0; nt < 4; ++nt)
        acc1[mt][nt] = mfma16(a[mt], bb[nt], acc1[mt][nt]);
  }
  __syncthreads();
  epi72(hb, acc1, cb1 + c * 64, wave, quad, l16);
  stage_w64(cW2t + (size_t)c * 64 * 64, wt, tid);
  __syncthreads();

  // ---- cp layer 2 ----
  f32x4 acc2[2][4]; zero_acc(acc2);
  gemm64(hb, wt, acc2, wave, quad, l16);
  __syncthreads();
  epi72(hb, acc2, cb2 + c * 64, wave, quad, l16);
  if (tid < 8) *(uint4*)&wt[tid * 8] = *(const uint4*)(cw3 + (size_t)c * 64 + tid * 8);
  __syncthreads();

  // ---- cp layer 3 (N=1 via MFMA; B nonzero only in lane col 0) ----
  f32x4 acc3[2];
  { const f32x4 z = {0.f, 0.f, 0.f, 0.f}; acc3[0] = z; acc3[1] = z; }
#pragma unroll
  for (int ks = 0; ks < 2; ++ks) {
    bf16x8 bb = {};
    if (l16 == 0) bb = *(const bf16x8*)&wt[ks * 32 + quad * 8];
#pragma unroll
    for (int mt = 0; mt < 2; ++mt) {
      bf16x8 a = *(const bf16x8*)&hb[(wave * 32 + mt * 16 + l16) * 72 + ks * 32 + quad * 8];
      acc3[mt] = mfma16(a, bb, acc3[mt]);
    }
  }
  if (l16 == 0) {
    float bv = cb3[c];
#pragma unroll
    for (int mt = 0; mt < 2; ++mt)
#pragma unroll
      for (int r = 0; r < 4; ++r)
        sm.conc[wave * 32 + mt * 16 + quad * 4 + r] = acc3[mt][r] + bv;
  }
  __syncthreads();

  // ---- gate + outputs (fp32) ----
  for (int ii = tid; ii < BM_ * E_; ii += 256) {
    int row = ii >> 4, e = ii & 15;
    float cv = sm.conc[row];
    float w  = fminf(fmaxf(cv * 0.5f + 0.5f, 0.f), 1.f);
    float pv2 = (float)sm.xcb[row * 40 + e];
    float nv2 = (float)sm.xcb[row * 40 + 16 + e];
    out_emb[(size_t)(row0 + row) * (E_ * C_) + e * C_ + c] = pv2 * w + nv2 * (1.f - w);
  }
  if (tid < 128) out_con[(size_t)(row0 + tid) * C_ + c] = sm.conc[tid];
}

// ------------- prep_all: ONE flat 1D launch, no dead blocks -------------------
// Blocks [0, tblocks): LDS-tiled transpose of [C][K][64] fp32 -> [C][64][K] bf16.
// Blocks [tblocks, ..): grid-strided (4 chunks/thread) fp32->bf16 copies and
//   small strided transposes.
#define TSEG 5
#define PSEG 5
struct PrepArgs {
  const float* tsrc[TSEG];
  __bf16*      tdst[TSEG];
  int tstart[TSEG + 1];
  int ktiles[TSEG];            // K/64
  const float* psrc[PSEG];
  __bf16*      pdst[PSEG];
  int pstart[PSEG + 1];        // block starts (after tblocks)
  int pchunks[PSEG];           // total 8-elem chunks in segment
  int kdiv8[PSEG];
  int N[PSEG];                 // 1 = plain copy, else transpose inner stride
  int tblocks;
};

__global__ __launch_bounds__(256) void prep_all(PrepArgs a) {
  const int tid = threadIdx.x;
  const int b = blockIdx.x;
  __shared__ __bf16 lt[64 * 72];
  if (b < a.tblocks) {
    int s = 0;
    while (s < TSEG - 1 && b >= a.tstart[s + 1]) ++s;
    const int idx = b - a.tstart[s];
    const int kt = idx % a.ktiles[s];
    const int c  = idx / a.ktiles[s];
    const int K  = a.ktiles[s] * 64;
    const float* src = a.tsrc[s] + (size_t)c * K * 64 + (size_t)kt * 64 * 64;
    __bf16*      dst = a.tdst[s] + (size_t)c * 64 * K + kt * 64;
    const int r = tid >> 4, c4 = (tid & 15) * 4;
#pragma unroll
    for (int it = 0; it < 4; ++it) {
      int k = r + it * 16;
      float4 v = *(const float4*)(src + (size_t)k * 64 + c4);
      lt[(c4 + 0) * 72 + k] = (__bf16)v.x;
      lt[(c4 + 1) * 72 + k] = (__bf16)v.y;
      lt[(c4 + 2) * 72 + k] = (__bf16)v.z;
      lt[(c4 + 3) * 72 + k] = (__bf16)v.w;
    }
    __syncthreads();
    const int n = tid >> 3, i = tid & 7;
#pragma unroll
    for (int it = 0; it < 2; ++it) {
      int nn = n + it * 32;
      *(uint4*)(dst + (size_t)nn * K + i * 8) = *(const uint4*)&lt[nn * 72 + i * 8];
    }
  } else {
    const int bb = b - a.tblocks;
    int s = 0;
    while (s < PSEG - 1 && bb >= a.pstart[s + 1]) ++s;
    const int lb  = bb - a.pstart[s];
    const int nch = a.pchunks[s];
    const int kc  = a.kdiv8[s];
    const int N   = a.N[s];
#pragma unroll
    for (int j = 0; j < 4; ++j) {
      const int li = (lb * 4 + j) * 256 + tid;
      if (li >= nch) break;
      if (N == 1) {
        const float4* src = (const float4*)a.psrc[s] + (size_t)li * 2;
        float4 v0 = src[0], v1 = src[1];
        *(uint4*)(a.pdst[s] + (size_t)li * 8) = __builtin_bit_cast(uint4, cvt8(v0, v1));
      } else {
        int rn = li / kc;
        int k0 = (li - rn * kc) * 8;
        int cc = rn / N;
        int n  = rn - cc * N;
        const float* src = a.psrc[s] + ((size_t)cc * kc * 8 + k0) * N + n;
        bf16x8 r;
#pragma unroll
        for (int jj = 0; jj < 8; ++jj) r[jj] = (__bf16)src[(size_t)jj * N];
        *(uint4*)(a.pdst[s] + (size_t)rn * kc * 8 + k0) = __builtin_bit_cast(uint4, r);
      }
    }
  }
}

// ============================== launch =======================================
extern "C" void kernel_launch(void* const* d_in, const int* in_sizes, int n_in,
                              void* d_out, int out_size, void* d_ws, size_t ws_size,
                              hipStream_t stream) {
  const float* xf   = (const float*)d_in[0];
  const float* pW1f = (const float*)d_in[1];
  const float* pb1f = (const float*)d_in[2];
  const float* pW2f = (const float*)d_in[3];
  const float* pb2f = (const float*)d_in[4];
  const float* pW3f = (const float*)d_in[5];
  const float* pb3f = (const float*)d_in[6];
  const float* nW1f = (const float*)d_in[7];
  const float* nb1f = (const float*)d_in[8];
  const float* nW2f = (const float*)d_in[9];
  const float* nb2f = (const float*)d_in[10];
  const float* nW3f = (const float*)d_in[11];
  const float* nb3f = (const float*)d_in[12];
  const float* cW1f = (const float*)d_in[13];
  const float* cb1f = (const float*)d_in[14];
  const float* cW2f = (const float*)d_in[15];
  const float* cb2f = (const float*)d_in[16];
  const float* cW3f = (const float*)d_in[17];
  const float* cb3f = (const float*)d_in[18];

  float* out_emb = (float*)d_out;
  float* out_con = out_emb + (size_t)B_ * E_ * C_;

  const int cx   = B_ * IN_;          // 6291456
  const int cW1c = C_ * IN_ * H_;     // 3145728
  const int cW2c = C_ * H_ * H_;      // 262144
  const int cW3c = C_ * H_ * E_;      // 65536
  const int ccW1 = C_ * 2 * E_ * H_;  // 131072
  const int ccW3 = C_ * H_;           // 4096

  __bf16* w = (__bf16*)d_ws;
  size_t o = 0;
  __bf16* xw   = w + o; o += cx;
  __bf16* pw1t = w + o; o += cW1c;
  __bf16* nw1t = w + o; o += cW1c;
  __bf16* pw2t = w + o; o += cW2c;
  __bf16* nw2t = w + o; o += cW2c;
  __bf16* cw2t = w + o; o += cW2c;
  __bf16* pw3t = w + o; o += cW3c;
  __bf16* nw3t = w + o; o += cW3c;
  __bf16* cw1t = w + o; o += ccW1;
  __bf16* cw3w = w + o; o += ccW3;

  PrepArgs a;
  int tb = 0, pb = 0;
  {
    const float* tsrc[TSEG] = {pW1f, nW1f, pW2f, nW2f, cW2f};
    __bf16*      tdst[TSEG] = {pw1t, nw1t, pw2t, nw2t, cw2t};
    const int    tk[TSEG]   = {12,   12,   1,    1,    1};
    for (int i = 0; i < TSEG; ++i) {
      a.tsrc[i] = tsrc[i]; a.tdst[i] = tdst[i]; a.ktiles[i] = tk[i];
      a.tstart[i] = tb;
      tb += tk[i] * C_;
    }
    a.tstart[TSEG] = tb;
    a.tblocks = tb;

    const float* psrc[PSEG] = {xf, cW3f, pW3f, nW3f, cW1f};
    __bf16*      pdst[PSEG] = {xw, cw3w, pw3t, nw3t, cw1t};
    const int    pKs[PSEG]  = {0,  0,    64,   64,   32};
    const int    pNs[PSEG]  = {1,  1,    16,   16,   64};
    const int    pels[PSEG] = {cx, ccW3, cW3c, cW3c, ccW1};
    for (int i = 0; i < PSEG; ++i) {
      a.psrc[i] = psrc[i]; a.pdst[i] = pdst[i];
      a.pchunks[i] = pels[i] / 8;
      a.kdiv8[i] = (pNs[i] == 1) ? (pels[i] / 8) : (pKs[i] / 8);
      a.N[i] = pNs[i];
      a.pstart[i] = pb;
      pb += (pels[i] / 8 + 1023) / 1024;   // 256 threads x 4 chunks per block
    }
    a.pstart[PSEG] = pb;
  }
  prep_all<<<tb + pb, 256, 0, stream>>>(a);

  dim3 grid(B_ / BM_, C_);
  cb_fused_t<<<grid, 256, 0, stream>>>(xw,
      pw1t, pb1f, pw2t, pb2f, pw3t, pb3f,
      nw1t, nb1f, nw2t, nb2f, nw3t, nb3f,
      cw1t, cb1f, cw2t, cb2f, cw3w, cb3f,
      out_emb, out_con);
}